// Round 2
// baseline (597.299 us; speedup 1.0000x reference)
//
#include <hip/hip_runtime.h>
#include <math.h>

#define CLIP_EPS 1e-9
#define HULL_TOL -1e-7

struct DP { double x, y; };

__device__ __forceinline__ double crossd(const DP& a, const DP& b, const DP& c) {
    return (b.x - a.x) * (c.y - a.y) - (b.y - a.y) * (c.x - a.x);
}

// Shoelace signed area over n points (polygon closes n-1 -> 0).
__device__ __forceinline__ double shoelaced(const DP* p, int n) {
    double s = 0.0;
    for (int i = 0; i < n; i++) {
        int j = (i + 1 == n) ? 0 : i + 1;
        s += p[i].x * p[j].y - p[j].x * p[i].y;
    }
    return 0.5 * s;
}

// Reference-semantics convex hull:
//   on_hull[a] = exists b!=a s.t. all c: cross(b-a, c-a) >= -1e-7
//   order hull points by atan2 angle around centroid of hull points (stable).
// Degenerate (no hull points): reference returns pts[0] repeated -> emulate
// with out[0]=pts[0], m=1 (padding with last reproduces the repeat).
__device__ int hull_sorted(const DP* pts, int K, DP* out) {
    bool oh[13];
    double sx = 0.0, sy = 0.0;
    int cnt = 0;
    for (int a = 0; a < K; a++) {
        bool onh = false;
        for (int b = 0; b < K && !onh; b++) {
            if (b == a) continue;
            bool ok = true;
            for (int c = 0; c < K; c++) {
                double cr = crossd(pts[a], pts[b], pts[c]);
                if (!(cr >= HULL_TOL)) { ok = false; break; }
            }
            onh = ok;
        }
        oh[a] = onh;
        if (onh) { sx += pts[a].x; sy += pts[a].y; cnt++; }
    }
    double inv = 1.0 / fmax((double)cnt, 1.0);
    double cx = sx * inv, cy = sy * inv;

    // stable insertion sort of hull points by angle ascending
    double angs[13];
    int m = 0;
    for (int a = 0; a < K; a++) {
        if (!oh[a]) continue;
        double ang = atan2(pts[a].y - cy, pts[a].x - cx);
        int j = m;
        while (j > 0 && angs[j - 1] > ang) {
            angs[j] = angs[j - 1];
            out[j] = out[j - 1];
            j--;
        }
        angs[j] = ang;
        out[j] = pts[a];
        m++;
    }
    if (m == 0) { out[0] = pts[0]; m = 1; }
    return m;
}

__global__ __launch_bounds__(256)
void giou_kernel(const float* __restrict__ pred,
                 const float* __restrict__ target,
                 const float* __restrict__ weight,
                 float* __restrict__ out,
                 int n, double invN) {
    int i = blockIdx.x * blockDim.x + threadIdx.x;
    double loss = 0.0;
    if (i < n) {
        // ---- load target (4 pts) ----
        DP T[4];
        for (int k = 0; k < 4; k++) {
            T[k].x = (double)target[(size_t)i * 8 + 2 * k];
            T[k].y = (double)target[(size_t)i * 8 + 2 * k + 1];
        }
        double saT = shoelaced(T, 4);
        double areaB = fabs(saT);
        DP Tc[4];
        if (saT < 0.0) {
            Tc[0] = T[3]; Tc[1] = T[2]; Tc[2] = T[1]; Tc[3] = T[0];
        } else {
            Tc[0] = T[0]; Tc[1] = T[1]; Tc[2] = T[2]; Tc[3] = T[3];
        }

        // ---- load pred (9 pts) ----
        DP P[9];
        for (int k = 0; k < 9; k++) {
            P[k].x = (double)pred[(size_t)i * 18 + 2 * k];
            P[k].y = (double)pred[(size_t)i * 18 + 2 * k + 1];
        }

        // ---- hull of P ----
        DP hullA[9];
        int m = hull_sorted(P, 9, hullA);
        double areaA = fabs(shoelaced(hullA, m));

        // ---- subject polygon: m hull pts + pad to 16 with last ----
        DP poly[16];
        for (int j = 0; j < m; j++) poly[j] = hullA[j];
        for (int j = m; j < 16; j++) poly[j] = hullA[m - 1];

        // ---- Sutherland-Hodgman clip by T_ccw, reference pad/truncate semantics ----
        for (int e = 0; e < 4; e++) {
            DP a = Tc[e];
            DP b = Tc[(e + 1) & 3];
            double ex = b.x - a.x, ey = b.y - a.y;

            DP keep[16];
            int nk = 0;
            DP lastf = {0.0, 0.0};
            DP first_cand = {0.0, 0.0};

            for (int s = 0; s < 16; s++) {
                DP p = poly[s];
                DP q = poly[(s + 1) & 15];
                double dp = ex * (p.y - a.y) - ey * (p.x - a.x);
                double dq = ex * (q.y - a.y) - ey * (q.x - a.x);
                bool inp = dp >= 0.0;
                bool inq = dq >= 0.0;
                double denom = dp - dq;
                double dd = (fabs(denom) < CLIP_EPS) ? CLIP_EPS : denom;
                double t = dp / dd;
                DP inter = { p.x + t * (q.x - p.x), p.y + t * (q.y - p.y) };
                if (s == 0) first_cand = inter;  // cand[0] in reference order
                if (inp != inq) {
                    if (nk < 16) keep[nk] = inter;
                    nk++;
                    lastf = inter;
                }
                if (inq) {
                    if (nk < 16) keep[nk] = q;
                    nk++;
                    lastf = q;
                }
            }
            if (nk == 0) lastf = first_cand;
            int lim = nk < 16 ? nk : 16;
            for (int j = 0; j < lim; j++) poly[j] = keep[j];
            for (int j = lim; j < 16; j++) poly[j] = lastf;
        }
        double interA = fabs(shoelaced(poly, 16));

        // ---- hull of P ++ T (original T order) ----
        DP C[13];
        for (int k = 0; k < 9; k++) C[k] = P[k];
        for (int k = 0; k < 4; k++) C[9 + k] = T[k];
        DP hullC[13];
        int mc = hull_sorted(C, 13, hullC);
        double areaC = fabs(shoelaced(hullC, mc));

        double uni = areaA + areaB - interA;
        double giou = interA / fmax(uni, CLIP_EPS)
                    - (areaC - uni) / fmax(areaC, CLIP_EPS);
        loss = (1.0 - giou) * (double)weight[i];
    }

    // ---- block reduction -> atomic ----
    double v = loss;
    #pragma unroll
    for (int off = 32; off > 0; off >>= 1) v += __shfl_down(v, off, 64);
    __shared__ double red[4];
    if ((threadIdx.x & 63) == 0) red[threadIdx.x >> 6] = v;
    __syncthreads();
    if (threadIdx.x == 0) {
        double s = red[0] + red[1] + red[2] + red[3];
        atomicAdd(out, (float)(s * invN));
    }
}

__global__ void zero_out_kernel(float* out) { *out = 0.f; }

extern "C" void kernel_launch(void* const* d_in, const int* in_sizes, int n_in,
                              void* d_out, int out_size, void* d_ws, size_t ws_size,
                              hipStream_t stream) {
    const float* pred = (const float*)d_in[0];
    const float* target = (const float*)d_in[1];
    const float* weight = (const float*)d_in[2];
    float* out = (float*)d_out;
    int n = in_sizes[2];  // weight has N elements

    zero_out_kernel<<<1, 1, 0, stream>>>(out);
    int block = 256;
    int grid = (n + block - 1) / block;
    giou_kernel<<<grid, block, 0, stream>>>(pred, target, weight, out, n, 1.0 / (double)n);
}

// Round 4
// 120.926 us; speedup vs baseline: 4.9394x; 4.9394x over previous
//
#include <hip/hip_runtime.h>
#include <math.h>

#define EPSD 1e-9
#define HULL_TOL -1e-7
#define BIGD 1e300

// Dynamic read from a register-resident f64 array via cndmask tree.
template<int K>
__device__ __forceinline__ double selK(const double (&a)[K], int idx) {
    double r = a[0];
#pragma unroll
    for (int j = 1; j < K; j++) r = (idx == j) ? a[j] : r;
    return r;
}

// Reference-semantics hull membership + stable angle sort.
//   on_hull[a] = exists b!=a s.t. all c: cross(b-a,c-a) >= -1e-7
//   key[a] = on_hull ? atan2(p-centroid_of_hull_pts) : +BIG
//   stable odd-even sort of (key, x, y); returns cnt (# hull points).
// Sorted points land in qx,qy (hull pts by angle first, then non-hull in
// original order). Degenerate cnt==0 matches reference (pts[0] everywhere
// via last-index clamp in the callers).
template<int K>
__device__ __forceinline__ int hull_sort(const double (&px)[K], const double (&py)[K],
                                         double (&qx)[K], double (&qy)[K]) {
    unsigned ohm = 0u;
    double sx = 0.0, sy = 0.0;
    int cnt = 0;
#pragma unroll 1
    for (int a = 0; a < K; a++) {
        double pax = selK<K>(px, a), pay = selK<K>(py, a);
        double dx[K], dy[K];
#pragma unroll
        for (int c = 0; c < K; c++) { dx[c] = px[c] - pax; dy[c] = py[c] - pay; }
        bool onh = false;
#pragma unroll
        for (int b = 0; b < K; b++) {
            double mn = BIGD;
#pragma unroll
            for (int c = 0; c < K; c++) {
                double cr = dx[b] * dy[c] - dy[b] * dx[c];
                mn = fmin(mn, cr);
            }
            onh = onh || ((b != a) && (mn >= HULL_TOL));
        }
        ohm |= (onh ? 1u : 0u) << a;
        sx += onh ? pax : 0.0;
        sy += onh ? pay : 0.0;
        cnt += onh ? 1 : 0;
    }
    double inv = 1.0 / fmax((double)cnt, 1.0);
    double mx = sx * inv, my = sy * inv;

    double key[K];
#pragma unroll
    for (int j = 0; j < K; j++) { key[j] = BIGD; qx[j] = px[j]; qy[j] = py[j]; }
#pragma unroll 1
    for (int a = 0; a < K; a++) {
        bool onh = (ohm >> a) & 1u;
        double ang = atan2(selK<K>(py, a) - my, selK<K>(px, a) - mx);
        double kv = onh ? ang : BIGD;
#pragma unroll
        for (int j = 0; j < K; j++) key[j] = (j == a) ? kv : key[j];
    }

    // stable odd-even transposition sort ((K+1) passes >= K needed)
#define CE_(j)                                                               \
    {                                                                        \
        bool sw = key[j] > key[(j) + 1];                                     \
        double t0 = key[j], t1 = qx[j], t2 = qy[j];                          \
        key[j] = sw ? key[(j) + 1] : t0;                                     \
        qx[j] = sw ? qx[(j) + 1] : t1;                                       \
        qy[j] = sw ? qy[(j) + 1] : t2;                                       \
        key[(j) + 1] = sw ? t0 : key[(j) + 1];                               \
        qx[(j) + 1] = sw ? t1 : qx[(j) + 1];                                 \
        qy[(j) + 1] = sw ? t2 : qy[(j) + 1];                                 \
    }
#pragma unroll 1
    for (int r = 0; r < (K + 1) / 2; r++) {
#pragma unroll
        for (int j = 0; j + 1 < K; j += 2) CE_(j);
#pragma unroll
        for (int j = 1; j + 1 < K; j += 2) CE_(j);
    }
#undef CE_
    return cnt;
}

// Signed area of the reference's padded hull output (pad-with-last == area
// of the first cnt points; consecutive duplicates contribute 0).
template<int K>
__device__ __forceinline__ double shoelace_cnt(const double (&x)[K], const double (&y)[K],
                                               int cnt) {
    int li = max(cnt - 1, 0);
    double lx = selK<K>(x, li), ly = selK<K>(y, li);
    double s = lx * y[0] - x[0] * ly;  // closing edge last->first
#pragma unroll
    for (int j = 0; j + 1 < K; j++) {
        double term = x[j] * y[j + 1] - x[j + 1] * y[j];
        s += (j + 1 < cnt) ? term : 0.0;
    }
    return 0.5 * s;
}

__global__ __launch_bounds__(64, 1)
void giou_kernel(const float* __restrict__ pred,
                 const float* __restrict__ target,
                 const float* __restrict__ weight,
                 float* __restrict__ out,
                 int n, double invN) {
    __shared__ double2 stk[64 * 17];  // per-thread clip stack, 17-slot stride
    const int tid = threadIdx.x;
    const int base = tid * 17;
    int i = blockIdx.x * 64 + tid;
    double loss = 0.0;
    if (i < n) {
        // ---- target (4 pts) ----
        double Tx[4], Ty[4];
        {
            const float4* tp = (const float4*)target + (size_t)i * 2;
            float4 t0 = tp[0], t1 = tp[1];
            Tx[0] = t0.x; Ty[0] = t0.y; Tx[1] = t0.z; Ty[1] = t0.w;
            Tx[2] = t1.x; Ty[2] = t1.y; Tx[3] = t1.z; Ty[3] = t1.w;
        }
        double saT = 0.5 * ((Tx[0] * Ty[1] - Tx[1] * Ty[0]) + (Tx[1] * Ty[2] - Tx[2] * Ty[1]) +
                            (Tx[2] * Ty[3] - Tx[3] * Ty[2]) + (Tx[3] * Ty[0] - Tx[0] * Ty[3]));
        double areaB = fabs(saT);
        bool rev = saT < 0.0;
        double tcx[4], tcy[4];
#pragma unroll
        for (int k = 0; k < 4; k++) {
            tcx[k] = rev ? Tx[3 - k] : Tx[k];
            tcy[k] = rev ? Ty[3 - k] : Ty[k];
        }

        // ---- pred (9 pts) ----
        double Px[9], Py[9];
        {
            const float2* pp = (const float2*)pred + (size_t)i * 9;
#pragma unroll
            for (int k = 0; k < 9; k++) { float2 v = pp[k]; Px[k] = v.x; Py[k] = v.y; }
        }

        // ---- hull of P ++ T (original T order) -> areaC ----
        double areaC;
        {
            double Cx[13], Cy[13];
#pragma unroll
            for (int k = 0; k < 9; k++) { Cx[k] = Px[k]; Cy[k] = Py[k]; }
#pragma unroll
            for (int k = 0; k < 4; k++) { Cx[9 + k] = Tx[k]; Cy[9 + k] = Ty[k]; }
            double sx13[13], sy13[13];
            int mc = hull_sort<13>(Cx, Cy, sx13, sy13);
            areaC = fabs(shoelace_cnt<13>(sx13, sy13, mc));
        }

        // ---- hull of P -> areaA + padded 16-pt subject polygon ----
        double qx[16], qy[16];
        double areaA;
        {
            double sx9[9], sy9[9];
            int m = hull_sort<9>(Px, Py, sx9, sy9);
            areaA = fabs(shoelace_cnt<9>(sx9, sy9, m));
            int li = max(m - 1, 0);
            double lx = selK<9>(sx9, li), ly = selK<9>(sy9, li);
#pragma unroll
            for (int j = 0; j < 16; j++) {
                bool v = (j < 9) && (j < m);
                qx[j] = v ? sx9[j < 9 ? j : 0] : lx;
                qy[j] = v ? sy9[j < 9 ? j : 0] : ly;
            }
        }

        // ---- Sutherland-Hodgman vs T_ccw, reference pad/truncate semantics ----
#pragma unroll 1
        for (int e = 0; e < 4; e++) {
            double ax = selK<4>(tcx, e), ay = selK<4>(tcy, e);
            int e1 = (e + 1) & 3;
            double bx = selK<4>(tcx, e1), by = selK<4>(tcy, e1);
            double ex_ = bx - ax, ey_ = by - ay;

            double d[16];
#pragma unroll
            for (int s = 0; s < 16; s++) d[s] = ex_ * (qy[s] - ay) - ey_ * (qx[s] - ax);

            int nk = 0;
            double lastx = 0.0, lasty = 0.0, fcx = 0.0, fcy = 0.0;
#pragma unroll
            for (int s = 0; s < 16; s++) {
                const int s1 = (s + 1) & 15;
                double dp = d[s], dq = d[s1];
                bool inp = dp >= 0.0, inq = dq >= 0.0;
                double den = dp - dq;
                double dd = (fabs(den) < EPSD) ? EPSD : den;
                double t = dp / dd;
                double ix = qx[s] + t * (qx[s1] - qx[s]);
                double iy = qy[s] + t * (qy[s1] - qy[s]);
                if (s == 0) { fcx = ix; fcy = iy; }  // cand[0] in reference order
                bool f1 = inp != inq;
                if (f1) {
                    if (nk < 16) stk[base + nk] = make_double2(ix, iy);
                    nk++;
                    lastx = ix; lasty = iy;
                }
                if (inq) {
                    if (nk < 16) stk[base + nk] = make_double2(qx[s1], qy[s1]);
                    nk++;
                    lastx = qx[s1]; lasty = qy[s1];
                }
            }
            bool any = nk > 0;
            double lx = any ? lastx : fcx;
            double ly = any ? lasty : fcy;
#pragma unroll
            for (int j = 0; j < 16; j++) {
                double2 v = stk[base + j];
                bool keep = j < nk;
                qx[j] = keep ? v.x : lx;
                qy[j] = keep ? v.y : ly;
            }
        }
        double sI = 0.0;
#pragma unroll
        for (int s = 0; s < 16; s++) {
            const int s1 = (s + 1) & 15;
            sI += qx[s] * qy[s1] - qx[s1] * qy[s];
        }
        double interA = fabs(0.5 * sI);

        double uni = areaA + areaB - interA;
        double giou = interA / fmax(uni, EPSD) - (areaC - uni) / fmax(areaC, EPSD);
        loss = (1.0 - giou) * (double)weight[i];
    }

    // ---- single-wave reduction -> atomic ----
    double v = loss;
#pragma unroll
    for (int off = 32; off > 0; off >>= 1) v += __shfl_down(v, off, 64);
    if (tid == 0) atomicAdd(out, (float)(v * invN));
}

__global__ void zero_out_kernel(float* out) { *out = 0.f; }

extern "C" void kernel_launch(void* const* d_in, const int* in_sizes, int n_in,
                              void* d_out, int out_size, void* d_ws, size_t ws_size,
                              hipStream_t stream) {
    const float* pred = (const float*)d_in[0];
    const float* target = (const float*)d_in[1];
    const float* weight = (const float*)d_in[2];
    float* out = (float*)d_out;
    int n = in_sizes[2];  // weight has N elements

    zero_out_kernel<<<1, 1, 0, stream>>>(out);
    int block = 64;
    int grid = (n + block - 1) / block;
    giou_kernel<<<grid, block, 0, stream>>>(pred, target, weight, out, n, 1.0 / (double)n);
}

// Round 5
// 91.097 us; speedup vs baseline: 6.5568x; 1.3274x over previous
//
#include <hip/hip_runtime.h>
#include <math.h>

#define EPSD 1e-9

// Odd-even transposition sort of (x,y) pairs by x (tie: y), K passes.
template<int K>
__device__ __forceinline__ void sortxy(double (&x)[K], double (&y)[K]) {
#pragma unroll
    for (int r = 0; r < K; r++) {
#pragma unroll
        for (int j = (r & 1); j + 1 < K; j += 2) {
            bool sw = (x[j] > x[j + 1]) || ((x[j] == x[j + 1]) && (y[j] > y[j + 1]));
            double tx = x[j], ty = y[j];
            x[j] = sw ? x[j + 1] : tx;
            y[j] = sw ? y[j + 1] : ty;
            x[j + 1] = sw ? tx : x[j + 1];
            y[j + 1] = sw ? ty : y[j + 1];
        }
    }
}

// Andrew monotone chain on points sorted by (x,y). CCW hull.
// Stack top-2 held in registers; deeper stack in per-thread LDS (stride 64).
// On return: Hb[0..m-1] (slot j at Hb[j*64]) = hull CCW from leftmost, m >= 2.
template<int K>
__device__ __forceinline__ int chain_hull(const double (&sx)[K], const double (&sy)[K],
                                          double2* Hb) {
    int k = 0;
    double t1x = 0.0, t1y = 0.0, t2x = 0.0, t2y = 0.0;
#define PUSH_(PX, PY)                                                         \
    {                                                                         \
        if (k >= 2) Hb[(k - 2) * 64] = make_double2(t2x, t2y);                \
        t2x = t1x; t2y = t1y; t1x = (PX); t1y = (PY); k++;                    \
    }
#define POPS_(PX, PY, LIM)                                                    \
    while (k >= (LIM) &&                                                      \
           ((t1x - t2x) * ((PY) - t2y) - (t1y - t2y) * ((PX) - t2x)) <= 0.0) {\
        k--;                                                                  \
        t1x = t2x; t1y = t2y;                                                 \
        if (k >= 2) { double2 v_ = Hb[(k - 2) * 64]; t2x = v_.x; t2y = v_.y; }\
    }
#pragma unroll
    for (int i = 0; i < K; i++) {          // lower chain
        double px = sx[i], py = sy[i];
        POPS_(px, py, 2);
        PUSH_(px, py);
    }
    const int lim = k + 1;
#pragma unroll
    for (int i = K - 2; i >= 0; i--) {     // upper chain
        double px = sx[i], py = sy[i];
        POPS_(px, py, lim);
        PUSH_(px, py);
    }
#undef PUSH_
#undef POPS_
    if (k >= 2) Hb[(k - 2) * 64] = make_double2(t2x, t2y);
    Hb[(k - 1) * 64] = make_double2(t1x, t1y);   // duplicate of H[0], dropped
    return k - 1;                                 // m hull points H[0..m-1]
}

__device__ __forceinline__ double hull_area(const double2* Hb, int m) {
    double2 f = Hb[0];
    double px = f.x, py = f.y, s = 0.0;
#pragma unroll 1
    for (int j = 1; j < m; j++) {
        double2 c = Hb[j * 64];
        s += px * c.y - c.x * py;
        px = c.x; py = c.y;
    }
    s += px * f.y - f.x * py;
    return 0.5 * s;
}

__global__ __launch_bounds__(64, 1)
void giou_kernel(const float* __restrict__ pred,
                 const float* __restrict__ target,
                 const float* __restrict__ weight,
                 float* __restrict__ out,
                 int n, double invN) {
    // per-thread LDS: 25 double2 slots, [slot][tid] layout (chain max 2*13-1)
    __shared__ double2 Hs[25 * 64];
    double2* Hb = &Hs[threadIdx.x];
    int i = blockIdx.x * 64 + threadIdx.x;
    double loss = 0.0;
    if (i < n) {
        // ---- target (4 pts) ----
        double Tx[4], Ty[4];
        {
            const float4* tp = (const float4*)target + (size_t)i * 2;
            float4 t0 = tp[0], t1 = tp[1];
            Tx[0] = t0.x; Ty[0] = t0.y; Tx[1] = t0.z; Ty[1] = t0.w;
            Tx[2] = t1.x; Ty[2] = t1.y; Tx[3] = t1.z; Ty[3] = t1.w;
        }
        double saT = 0.5 * ((Tx[0] * Ty[1] - Tx[1] * Ty[0]) + (Tx[1] * Ty[2] - Tx[2] * Ty[1]) +
                            (Tx[2] * Ty[3] - Tx[3] * Ty[2]) + (Tx[3] * Ty[0] - Tx[0] * Ty[3]));
        double areaB = fabs(saT);
        bool rev = saT < 0.0;
        double tcx[4], tcy[4];
#pragma unroll
        for (int k = 0; k < 4; k++) {
            tcx[k] = rev ? Tx[3 - k] : Tx[k];
            tcy[k] = rev ? Ty[3 - k] : Ty[k];
        }

        // ---- pred (9 pts) ----
        double Px[9], Py[9];
        {
            const float2* pp = (const float2*)pred + (size_t)i * 9;
#pragma unroll
            for (int k = 0; k < 9; k++) { float2 v = pp[k]; Px[k] = v.x; Py[k] = v.y; }
        }

        // ---- areaC: hull of P ++ T via sort + monotone chain ----
        double areaC;
        {
            double cx[13], cy[13];
#pragma unroll
            for (int k = 0; k < 9; k++) { cx[k] = Px[k]; cy[k] = Py[k]; }
#pragma unroll
            for (int k = 0; k < 4; k++) { cx[9 + k] = Tx[k]; cy[9 + k] = Ty[k]; }
            sortxy<13>(cx, cy);
            int mc = chain_hull<13>(cx, cy, Hb);
            areaC = fabs(hull_area(Hb, mc));
        }

        // ---- areaA + 16-pt padded subject polygon from hull(P) ----
        double qx[16], qy[16];
        double areaA;
        {
            double ax[9], ay[9];
#pragma unroll
            for (int k = 0; k < 9; k++) { ax[k] = Px[k]; ay[k] = Py[k]; }
            sortxy<9>(ax, ay);
            int m = chain_hull<9>(ax, ay, Hb);
            areaA = fabs(hull_area(Hb, m));
            // subject[j] = hull[min(j, m-1)]  (reference pad-with-last, rotated)
#pragma unroll
            for (int j = 0; j < 16; j++) {
                int idx = (j < m - 1) ? j : (m - 1);
                double2 v = Hb[idx * 64];
                qx[j] = v.x; qy[j] = v.y;
            }
        }

        // ---- Sutherland-Hodgman vs CCW rect, reference pad/truncate semantics ----
        // (Hb slots reused as the per-thread compaction stack.)
#pragma unroll
        for (int e = 0; e < 4; e++) {
            double ax = tcx[e], ay = tcy[e];
            double bx = tcx[(e + 1) & 3], by = tcy[(e + 1) & 3];
            double ex_ = bx - ax, ey_ = by - ay;

            double d[16];
#pragma unroll
            for (int s = 0; s < 16; s++) d[s] = ex_ * (qy[s] - ay) - ey_ * (qx[s] - ax);

            int nk = 0;
            double lastx = 0.0, lasty = 0.0, fcx = 0.0, fcy = 0.0;
#pragma unroll
            for (int s = 0; s < 16; s++) {
                const int s1 = (s + 1) & 15;
                double dp = d[s], dq = d[s1];
                bool inp = dp >= 0.0, inq = dq >= 0.0;
                double den = dp - dq;
                double dd = (fabs(den) < EPSD) ? EPSD : den;
                double t = dp / dd;
                double ix = qx[s] + t * (qx[s1] - qx[s]);
                double iy = qy[s] + t * (qy[s1] - qy[s]);
                if (s == 0) { fcx = ix; fcy = iy; }   // cand[0] in reference order
                bool f1 = inp != inq;
                if (f1) {
                    if (nk < 16) Hb[nk * 64] = make_double2(ix, iy);
                    nk++;
                    lastx = ix; lasty = iy;
                }
                if (inq) {
                    if (nk < 16) Hb[nk * 64] = make_double2(qx[s1], qy[s1]);
                    nk++;
                    lastx = qx[s1]; lasty = qy[s1];
                }
            }
            bool any = nk > 0;
            double lx = any ? lastx : fcx;
            double ly = any ? lasty : fcy;
#pragma unroll
            for (int j = 0; j < 16; j++) {
                double2 v = Hb[j * 64];
                bool keep = j < nk;
                qx[j] = keep ? v.x : lx;
                qy[j] = keep ? v.y : ly;
            }
        }
        double sI = 0.0;
#pragma unroll
        for (int s = 0; s < 16; s++) {
            const int s1 = (s + 1) & 15;
            sI += qx[s] * qy[s1] - qx[s1] * qy[s];
        }
        double interA = fabs(0.5 * sI);

        double uni = areaA + areaB - interA;
        double giou = interA / fmax(uni, EPSD) - (areaC - uni) / fmax(areaC, EPSD);
        loss = (1.0 - giou) * (double)weight[i];
    }

    // ---- single-wave reduction -> atomic ----
    double v = loss;
#pragma unroll
    for (int off = 32; off > 0; off >>= 1) v += __shfl_down(v, off, 64);
    if (threadIdx.x == 0) atomicAdd(out, (float)(v * invN));
}

__global__ void zero_out_kernel(float* out) { *out = 0.f; }

extern "C" void kernel_launch(void* const* d_in, const int* in_sizes, int n_in,
                              void* d_out, int out_size, void* d_ws, size_t ws_size,
                              hipStream_t stream) {
    const float* pred = (const float*)d_in[0];
    const float* target = (const float*)d_in[1];
    const float* weight = (const float*)d_in[2];
    float* out = (float*)d_out;
    int n = in_sizes[2];  // weight has N elements

    zero_out_kernel<<<1, 1, 0, stream>>>(out);
    int block = 64;
    int grid = (n + block - 1) / block;
    giou_kernel<<<grid, block, 0, stream>>>(pred, target, weight, out, n, 1.0 / (double)n);
}

// Round 7
// 82.371 us; speedup vs baseline: 7.2513x; 1.1059x over previous
//
#include <hip/hip_runtime.h>
#include <math.h>

#define EPSD 1e-9

// Odd-even transposition sort of (x,y) pairs by x (tie: y), K passes.
template<int K>
__device__ __forceinline__ void sortxy(double (&x)[K], double (&y)[K]) {
#pragma unroll
    for (int r = 0; r < K; r++) {
#pragma unroll
        for (int j = (r & 1); j + 1 < K; j += 2) {
            bool sw = (x[j] > x[j + 1]) || ((x[j] == x[j + 1]) && (y[j] > y[j + 1]));
            double tx = x[j], ty = y[j];
            x[j] = sw ? x[j + 1] : tx;
            y[j] = sw ? y[j + 1] : ty;
            x[j + 1] = sw ? tx : x[j + 1];
            y[j + 1] = sw ? ty : y[j + 1];
        }
    }
}

// Andrew monotone chain on points sorted by (x,y). CCW hull.  (round-5
// verbatim: top-2 register stack, deeper stack per-thread LDS stride 64.)
// On return: Hb[0..m-1] (slot j at Hb[j*64]) = hull CCW from leftmost, m >= 2.
// Exact-duplicate inputs produce cross==0 and are popped.
template<int K>
__device__ __forceinline__ int chain_hull(const double (&sx)[K], const double (&sy)[K],
                                          double2* Hb) {
    int k = 0;
    double t1x = 0.0, t1y = 0.0, t2x = 0.0, t2y = 0.0;
#define PUSH_(PX, PY)                                                         \
    {                                                                         \
        if (k >= 2) Hb[(k - 2) * 64] = make_double2(t2x, t2y);                \
        t2x = t1x; t2y = t1y; t1x = (PX); t1y = (PY); k++;                    \
    }
#define POPS_(PX, PY, LIM)                                                    \
    while (k >= (LIM) &&                                                      \
           ((t1x - t2x) * ((PY) - t2y) - (t1y - t2y) * ((PX) - t2x)) <= 0.0) {\
        k--;                                                                  \
        t1x = t2x; t1y = t2y;                                                 \
        if (k >= 2) { double2 v_ = Hb[(k - 2) * 64]; t2x = v_.x; t2y = v_.y; }\
    }
#pragma unroll
    for (int i = 0; i < K; i++) {          // lower chain
        double px = sx[i], py = sy[i];
        POPS_(px, py, 2);
        PUSH_(px, py);
    }
    const int lim = k + 1;
#pragma unroll
    for (int i = K - 2; i >= 0; i--) {     // upper chain
        double px = sx[i], py = sy[i];
        POPS_(px, py, lim);
        PUSH_(px, py);
    }
#undef PUSH_
#undef POPS_
    if (k >= 2) Hb[(k - 2) * 64] = make_double2(t2x, t2y);
    Hb[(k - 1) * 64] = make_double2(t1x, t1y);   // duplicate of H[0], dropped
    return k - 1;                                 // m hull points H[0..m-1]
}

// Lane pairs: even lane handles hull(P)+clip+loss, odd lane hull(P++T).
// Both lanes run the identical 13-pt sort+chain code (no hull divergence).
__global__ __launch_bounds__(64)
void giou_kernel(const float* __restrict__ pred,
                 const float* __restrict__ target,
                 const float* __restrict__ weight,
                 double* __restrict__ ws,
                 int n) {
    __shared__ double2 Hs[16 * 64];   // per-thread stack, [slot][tid], 16 KB
    double2* Hb = &Hs[threadIdx.x];
    const int lane = threadIdx.x;
    const int odd = lane & 1;
    const int i0 = blockIdx.x * 32 + (lane >> 1);
    const bool valid = i0 < n;
    const int i = valid ? i0 : (n > 0 ? n - 1 : 0);

    // ---- target (4 pts) ----
    double Tx[4], Ty[4];
    {
        const float4* tp = (const float4*)target + (size_t)i * 2;
        float4 t0 = tp[0], t1 = tp[1];
        Tx[0] = t0.x; Ty[0] = t0.y; Tx[1] = t0.z; Ty[1] = t0.w;
        Tx[2] = t1.x; Ty[2] = t1.y; Tx[3] = t1.z; Ty[3] = t1.w;
    }
    double saT = 0.5 * ((Tx[0] * Ty[1] - Tx[1] * Ty[0]) + (Tx[1] * Ty[2] - Tx[2] * Ty[1]) +
                        (Tx[2] * Ty[3] - Tx[3] * Ty[2]) + (Tx[3] * Ty[0] - Tx[0] * Ty[3]));
    double areaB = fabs(saT);
    bool rev = saT < 0.0;
    double tcx[4], tcy[4];
#pragma unroll
    for (int k = 0; k < 4; k++) {
        tcx[k] = rev ? Tx[3 - k] : Tx[k];
        tcy[k] = rev ? Ty[3 - k] : Ty[k];
    }

    // ---- 13-pt working set: P ++ (odd ? T : exact dups of P[0]) ----
    double X[13], Y[13];
    {
        const float2* pp = (const float2*)pred + (size_t)i * 9;
#pragma unroll
        for (int k = 0; k < 9; k++) { float2 v = pp[k]; X[k] = v.x; Y[k] = v.y; }
    }
#pragma unroll
    for (int k = 0; k < 4; k++) {
        X[9 + k] = odd ? Tx[k] : X[0];
        Y[9 + k] = odd ? Ty[k] : Y[0];
    }

    // ---- sort + chain hull (identical code both lanes) ----
    sortxy<13>(X, Y);
    int m = chain_hull<13>(X, Y, Hb);

    // ---- padded 16-pt polygon (reference pad-with-last, rotated) ----
    double qx[16], qy[16];
#pragma unroll
    for (int j = 0; j < 16; j++) {
        int idx = (j < m - 1) ? j : (m - 1);
        double2 v = Hb[idx * 64];
        qx[j] = v.x; qy[j] = v.y;
    }
    double sA = 0.0;
#pragma unroll
    for (int s = 0; s < 16; s++) {
        const int s1 = (s + 1) & 15;
        sA += qx[s] * qy[s1] - qx[s1] * qy[s];
    }
    double area = fabs(0.5 * sA);           // even: areaA, odd: areaC
    double other = __shfl_xor(area, 1, 64);
    double areaA = odd ? other : area;      // (odd-lane value unused)
    double areaC = odd ? area : other;

    // ---- Sutherland-Hodgman vs CCW rect (round-5 verbatim semantics) ----
#pragma unroll
    for (int e = 0; e < 4; e++) {
        double ax = tcx[e], ay = tcy[e];
        double bx = tcx[(e + 1) & 3], by = tcy[(e + 1) & 3];
        double ex_ = bx - ax, ey_ = by - ay;

        double d[16];
#pragma unroll
        for (int s = 0; s < 16; s++) d[s] = ex_ * (qy[s] - ay) - ey_ * (qx[s] - ax);

        int nk = 0;
        double lastx = 0.0, lasty = 0.0, fcx = 0.0, fcy = 0.0;
#pragma unroll
        for (int s = 0; s < 16; s++) {
            const int s1 = (s + 1) & 15;
            double dp = d[s], dq = d[s1];
            bool inp = dp >= 0.0, inq = dq >= 0.0;
            double den = dp - dq;
            double dd = (fabs(den) < EPSD) ? EPSD : den;
            double t = dp / dd;
            double ix = qx[s] + t * (qx[s1] - qx[s]);
            double iy = qy[s] + t * (qy[s1] - qy[s]);
            if (s == 0) { fcx = ix; fcy = iy; }   // cand[0] in reference order
            bool f1 = inp != inq;
            if (f1) {
                if (nk < 16) Hb[nk * 64] = make_double2(ix, iy);
                nk++;
                lastx = ix; lasty = iy;
            }
            if (inq) {
                if (nk < 16) Hb[nk * 64] = make_double2(qx[s1], qy[s1]);
                nk++;
                lastx = qx[s1]; lasty = qy[s1];
            }
        }
        bool any = nk > 0;
        double lx = any ? lastx : fcx;
        double ly = any ? lasty : fcy;
#pragma unroll
        for (int j = 0; j < 16; j++) {
            double2 v = Hb[j * 64];
            bool keep = j < nk;
            qx[j] = keep ? v.x : lx;
            qy[j] = keep ? v.y : ly;
        }
    }
    double sI = 0.0;
#pragma unroll
    for (int s = 0; s < 16; s++) {
        const int s1 = (s + 1) & 15;
        sI += qx[s] * qy[s1] - qx[s1] * qy[s];
    }
    double interA = fabs(0.5 * sI);

    double uni = areaA + areaB - interA;
    double giou = interA / fmax(uni, EPSD) - (areaC - uni) / fmax(areaC, EPSD);
    double loss = (1.0 - giou) * (double)weight[i];
    double contrib = (!odd && valid) ? loss : 0.0;

    // ---- single-wave reduction -> per-block partial ----
#pragma unroll
    for (int off = 32; off > 0; off >>= 1) contrib += __shfl_down(contrib, off, 64);
    if (lane == 0) ws[blockIdx.x] = contrib;
}

__global__ __launch_bounds__(256)
void reduce_kernel(const double* __restrict__ ws, float* __restrict__ out,
                   int nb, double invN) {
    int t = threadIdx.x;
    double s = 0.0;
    for (int j = t; j < nb; j += 256) s += ws[j];
#pragma unroll
    for (int off = 32; off > 0; off >>= 1) s += __shfl_down(s, off, 64);
    __shared__ double red[4];
    if ((t & 63) == 0) red[t >> 6] = s;
    __syncthreads();
    if (t == 0) out[0] = (float)((red[0] + red[1] + red[2] + red[3]) * invN);
}

extern "C" void kernel_launch(void* const* d_in, const int* in_sizes, int n_in,
                              void* d_out, int out_size, void* d_ws, size_t ws_size,
                              hipStream_t stream) {
    const float* pred = (const float*)d_in[0];
    const float* target = (const float*)d_in[1];
    const float* weight = (const float*)d_in[2];
    float* out = (float*)d_out;
    double* ws = (double*)d_ws;
    int n = in_sizes[2];  // weight has N elements

    int grid = (n + 31) / 32;  // 32 instances per 64-thread block (lane pairs)
    giou_kernel<<<grid, 64, 0, stream>>>(pred, target, weight, ws, n);
    reduce_kernel<<<1, 256, 0, stream>>>(ws, out, grid, 1.0 / (double)n);
}

// Round 8
// 81.018 us; speedup vs baseline: 7.3724x; 1.0167x over previous
//
#include <hip/hip_runtime.h>
#include <math.h>

#define EPSD 1e-9

// Odd-even transposition sort of (x,y) pairs by x (tie: y), K passes.
template<int K>
__device__ __forceinline__ void sortxy(double (&x)[K], double (&y)[K]) {
#pragma unroll
    for (int r = 0; r < K; r++) {
#pragma unroll
        for (int j = (r & 1); j + 1 < K; j += 2) {
            bool sw = (x[j] > x[j + 1]) || ((x[j] == x[j + 1]) && (y[j] > y[j + 1]));
            double tx = x[j], ty = y[j];
            x[j] = sw ? x[j + 1] : tx;
            y[j] = sw ? y[j + 1] : ty;
            x[j + 1] = sw ? tx : x[j + 1];
            y[j + 1] = sw ? ty : y[j + 1];
        }
    }
}

// Andrew monotone chain on points sorted by (x,y). CCW hull. (round-7
// verbatim: top-2 register stack, deeper stack per-thread LDS stride 64.)
// On return: Hb[0..m-1] (slot j at Hb[j*64]) = hull CCW from leftmost, m >= 2.
// Max stack depth <= hull_size+2 <= 15 (16 slots safe; validated r5/r7).
template<int K>
__device__ __forceinline__ int chain_hull(const double (&sx)[K], const double (&sy)[K],
                                          double2* Hb) {
    int k = 0;
    double t1x = 0.0, t1y = 0.0, t2x = 0.0, t2y = 0.0;
#define PUSH_(PX, PY)                                                         \
    {                                                                         \
        if (k >= 2) Hb[(k - 2) * 64] = make_double2(t2x, t2y);                \
        t2x = t1x; t2y = t1y; t1x = (PX); t1y = (PY); k++;                    \
    }
#define POPS_(PX, PY, LIM)                                                    \
    while (k >= (LIM) &&                                                      \
           ((t1x - t2x) * ((PY) - t2y) - (t1y - t2y) * ((PX) - t2x)) <= 0.0) {\
        k--;                                                                  \
        t1x = t2x; t1y = t2y;                                                 \
        if (k >= 2) { double2 v_ = Hb[(k - 2) * 64]; t2x = v_.x; t2y = v_.y; }\
    }
#pragma unroll
    for (int i = 0; i < K; i++) {          // lower chain
        double px = sx[i], py = sy[i];
        POPS_(px, py, 2);
        PUSH_(px, py);
    }
    const int lim = k + 1;
#pragma unroll
    for (int i = K - 2; i >= 0; i--) {     // upper chain
        double px = sx[i], py = sy[i];
        POPS_(px, py, lim);
        PUSH_(px, py);
    }
#undef PUSH_
#undef POPS_
    if (k >= 2) Hb[(k - 2) * 64] = make_double2(t2x, t2y);
    Hb[(k - 1) * 64] = make_double2(t1x, t1y);   // duplicate of H[0], dropped
    return k - 1;                                 // m hull points H[0..m-1]
}

// Lane pairs: even lane hull(P); odd lane hull(P++T). Intersection area via
// boundary line-integral: even lane sums hullA edges clipped inside T
// (Liang-Barsky vs 4 planes), odd lane sums T edges clipped inside hullA
// (partner hull read cross-lane from LDS). Exact for convex polygons.
__global__ __launch_bounds__(64)
void giou_kernel(const float* __restrict__ pred,
                 const float* __restrict__ target,
                 const float* __restrict__ weight,
                 double* __restrict__ ws,
                 int n) {
    __shared__ double2 Hs[16 * 64];   // per-thread hull, [slot][tid], 16 KB
    double2* Hb = &Hs[threadIdx.x];
    const int lane = threadIdx.x;
    const int odd = lane & 1;
    const int i0 = blockIdx.x * 32 + (lane >> 1);
    const bool valid = i0 < n;
    const int i = valid ? i0 : (n > 0 ? n - 1 : 0);

    // ---- target (4 pts) ----
    double Tx[4], Ty[4];
    {
        const float4* tp = (const float4*)target + (size_t)i * 2;
        float4 t0 = tp[0], t1 = tp[1];
        Tx[0] = t0.x; Ty[0] = t0.y; Tx[1] = t0.z; Ty[1] = t0.w;
        Tx[2] = t1.x; Ty[2] = t1.y; Tx[3] = t1.z; Ty[3] = t1.w;
    }
    double saT = 0.5 * ((Tx[0] * Ty[1] - Tx[1] * Ty[0]) + (Tx[1] * Ty[2] - Tx[2] * Ty[1]) +
                        (Tx[2] * Ty[3] - Tx[3] * Ty[2]) + (Tx[3] * Ty[0] - Tx[0] * Ty[3]));
    double areaB = fabs(saT);
    bool rev = saT < 0.0;
    double tcx[4], tcy[4];   // CCW target
#pragma unroll
    for (int k = 0; k < 4; k++) {
        tcx[k] = rev ? Tx[3 - k] : Tx[k];
        tcy[k] = rev ? Ty[3 - k] : Ty[k];
    }

    // ---- 13-pt working set: P ++ (odd ? T : exact dups of P[0]) ----
    double X[13], Y[13];
    {
        const float2* pp = (const float2*)pred + (size_t)i * 9;
#pragma unroll
        for (int k = 0; k < 9; k++) { float2 v = pp[k]; X[k] = v.x; Y[k] = v.y; }
    }
#pragma unroll
    for (int k = 0; k < 4; k++) {
        X[9 + k] = odd ? Tx[k] : X[0];
        Y[9 + k] = odd ? Ty[k] : Y[0];
    }

    // ---- sort + chain hull (identical code both lanes) ----
    sortxy<13>(X, Y);
    int m = chain_hull<13>(X, Y, Hb);

    // ---- own hull area ----
    double area;
    {
        double2 h0 = Hb[0];
        double px = h0.x, py = h0.y, s = 0.0;
#pragma unroll 1
        for (int j = 1; j < m; j++) {
            double2 c = Hb[j * 64];
            s += px * c.y - c.x * py;
            px = c.x; py = c.y;
        }
        s += px * h0.y - h0.x * py;
        area = fabs(0.5 * s);
    }
    double other = __shfl_xor(area, 1, 64);
    double areaA = odd ? other : area;
    double areaC = odd ? area : other;
    int mo = __shfl_xor(m, 1, 64);
    const int mA = odd ? mo : m;            // even lane's hull size (hull of P)
    __syncthreads();                         // partner hull visible in LDS
    const double2* HA = odd ? &Hs[lane - 1] : Hb;   // even lane's hull

    // ---- intersection boundary integral ----
    double S = 0.0;
    if (!odd) {
        // hullA edges clipped by T's 4 CCW half-planes (Liang-Barsky, exact)
#pragma unroll 1
        for (int j = 0; j < mA; j++) {
            double2 p = HA[j * 64];
            int j1 = (j + 1 == mA) ? 0 : j + 1;
            double2 q = HA[j1 * 64];
            double lo = 0.0, hi = 1.0;
#pragma unroll
            for (int e = 0; e < 4; e++) {
                double ax = tcx[e], ay = tcy[e];
                int e1 = (e + 1) & 3;
                double ex_ = tcx[e1] - ax, ey_ = tcy[e1] - ay;
                double s0 = ex_ * (p.y - ay) - ey_ * (p.x - ax);
                double s1 = ex_ * (q.y - ay) - ey_ * (q.x - ax);
                bool in0 = s0 >= 0.0, in1 = s1 >= 0.0;
                if (!in0 && !in1) { lo = 1.0; hi = 0.0; }
                else if (in0 != in1) {
                    double t = s0 / (s0 - s1);   // signs differ -> t in [0,1]
                    if (!in0) lo = fmax(lo, t); else hi = fmin(hi, t);
                }
            }
            if (lo < hi) {
                double dx_ = q.x - p.x, dy_ = q.y - p.y;
                double A0x = p.x + lo * dx_, A0y = p.y + lo * dy_;
                double B0x = p.x + hi * dx_, B0y = p.y + hi * dy_;
                S += A0x * B0y - B0x * A0y;
            }
        }
    } else if (mA >= 2) {
        // T's 4 edges clipped by hullA's half-planes
        double lo[4] = {0.0, 0.0, 0.0, 0.0}, hi[4] = {1.0, 1.0, 1.0, 1.0};
#pragma unroll 1
        for (int j = 0; j < mA; j++) {
            double2 a = HA[j * 64];
            int j1 = (j + 1 == mA) ? 0 : j + 1;
            double2 b = HA[j1 * 64];
            double ex_ = b.x - a.x, ey_ = b.y - a.y;
#pragma unroll
            for (int k = 0; k < 4; k++) {
                int k1 = (k + 1) & 3;
                double s0 = ex_ * (tcy[k] - a.y) - ey_ * (tcx[k] - a.x);
                double s1 = ex_ * (tcy[k1] - a.y) - ey_ * (tcx[k1] - a.x);
                bool in0 = s0 >= 0.0, in1 = s1 >= 0.0;
                if (!in0 && !in1) { lo[k] = 1.0; hi[k] = 0.0; }
                else if (in0 != in1) {
                    double t = s0 / (s0 - s1);
                    if (!in0) lo[k] = fmax(lo[k], t); else hi[k] = fmin(hi[k], t);
                }
            }
        }
#pragma unroll
        for (int k = 0; k < 4; k++) {
            if (lo[k] < hi[k]) {
                int k1 = (k + 1) & 3;
                double dx_ = tcx[k1] - tcx[k], dy_ = tcy[k1] - tcy[k];
                double A0x = tcx[k] + lo[k] * dx_, A0y = tcy[k] + lo[k] * dy_;
                double B0x = tcx[k] + hi[k] * dx_, B0y = tcy[k] + hi[k] * dy_;
                S += A0x * B0y - B0x * A0y;
            }
        }
    }
    double So = __shfl_xor(S, 1, 64);
    double inter = fabs(0.5 * (S + So));

    double uni = areaA + areaB - inter;
    double giou = inter / fmax(uni, EPSD) - (areaC - uni) / fmax(areaC, EPSD);
    double loss = (1.0 - giou) * (double)weight[i];
    double contrib = (!odd && valid) ? loss : 0.0;

    // ---- single-wave reduction -> per-block partial ----
#pragma unroll
    for (int off = 32; off > 0; off >>= 1) contrib += __shfl_down(contrib, off, 64);
    if (lane == 0) ws[blockIdx.x] = contrib;
}

__global__ __launch_bounds__(256)
void reduce_kernel(const double* __restrict__ ws, float* __restrict__ out,
                   int nb, double invN) {
    int t = threadIdx.x;
    double s = 0.0;
    for (int j = t; j < nb; j += 256) s += ws[j];
#pragma unroll
    for (int off = 32; off > 0; off >>= 1) s += __shfl_down(s, off, 64);
    __shared__ double red[4];
    if ((t & 63) == 0) red[t >> 6] = s;
    __syncthreads();
    if (t == 0) out[0] = (float)((red[0] + red[1] + red[2] + red[3]) * invN);
}

extern "C" void kernel_launch(void* const* d_in, const int* in_sizes, int n_in,
                              void* d_out, int out_size, void* d_ws, size_t ws_size,
                              hipStream_t stream) {
    const float* pred = (const float*)d_in[0];
    const float* target = (const float*)d_in[1];
    const float* weight = (const float*)d_in[2];
    float* out = (float*)d_out;
    double* ws = (double*)d_ws;
    int n = in_sizes[2];  // weight has N elements

    int grid = (n + 31) / 32;  // 32 instances per 64-thread block (lane pairs)
    giou_kernel<<<grid, 64, 0, stream>>>(pred, target, weight, ws, n);
    reduce_kernel<<<1, 256, 0, stream>>>(ws, out, grid, 1.0 / (double)n);
}